// Round 1
// baseline (794.627 us; speedup 1.0000x reference)
//
#include <hip/hip_runtime.h>
#include <math.h>

// Sinkhorn-divergence triplet loss (geomloss-style), MI355X.
// Strategy: (1) prep norms + log-weights, (2) three tiled cost kernels writing
// C/eps*log2e into workspace, (3) three block-resident log2-domain Sinkhorn
// kernels (C staged in LDS, f/g in LDS, two-pass LSE with native exp2/log2),
// (4) tiny finalize kernel.

namespace {
constexpr int NB = 128, NL = 128, ND = 300, NK = 10, NR = 50, NITER = 20;
constexpr float LOG2E   = 1.4426950408889634f;
constexpr float EPS     = 0.0025f;                  // blur^p = 0.05^2
constexpr float CSCALE  = 0.5f * LOG2E / EPS;       // squared-dist -> log2-domain cost
constexpr float VSCALE  = EPS * 0.6931471805599453f; // F2 -> f  (eps*ln2)
constexpr float LOG2_50 = 5.6438561897747395f;      // log2(50)
constexpr float NEGL2   = -1.442695e9f;             // -1e9 * log2e
}

// ---------------------------------------------------------------- prep
__global__ void prep_kernel(const float* __restrict__ anchor,
                            const float* __restrict__ weight,
                            const float* __restrict__ t0,
                            const int* __restrict__ len,
                            float* __restrict__ na, float* __restrict__ nt,
                            float* __restrict__ lw2) {
  int wid  = (blockIdx.x * blockDim.x + threadIdx.x) >> 6;
  int lane = threadIdx.x & 63;
  const int nA = NB * NL;
  const int total = nA + NK * NR;
  if (wid >= total) return;
  const float* src = (wid < nA) ? (anchor + (size_t)wid * ND)
                                : (t0 + (size_t)(wid - nA) * ND);
  float s = 0.f;
  for (int d = lane; d < ND; d += 64) { float v = src[d]; s += v * v; }
  #pragma unroll
  for (int off = 32; off; off >>= 1) s += __shfl_xor(s, off);
  if (lane == 0) { if (wid < nA) na[wid] = s; else nt[wid - nA] = s; }
  if (wid < nA && lane == 1) {
    int b = wid >> 7, l = wid & 127;
    float w = weight[wid];
    lw2[wid] = (l < len[b]) ? log2f(fmaxf(w, 1e-12f)) : NEGL2;
  }
}

// ---------------------------------------------------------------- cost
// mode 0: ab (pair p = b*NK+k, X=anchor rows b*NL.., Y=t0 rows k*NR..), n=NL m=NR
// mode 1: aa (pair b), n=m=NL
// mode 2: tt (pair p = i*NK+j), n=m=NR
__global__ __launch_bounds__(256)
void cost_kernel(const float* __restrict__ X, const float* __restrict__ Y,
                 const float* __restrict__ NX, const float* __restrict__ NY,
                 float* __restrict__ C, int n, int m, int mode) {
  __shared__ float Xs[32][17];
  __shared__ float Ys[32][17];
  int p = blockIdx.x;
  int i0 = blockIdx.y * 32, j0 = blockIdx.z * 32;
  int xr0, yr0;
  if (mode == 0)      { xr0 = (p / NK) * NL; yr0 = (p % NK) * NR; }
  else if (mode == 1) { xr0 = p * NL;        yr0 = xr0;           }
  else                { xr0 = (p / NK) * NR; yr0 = (p % NK) * NR; }
  size_t cbase = (size_t)p * n * m;

  int t  = threadIdx.x;
  int tx = t & 15, ty = t >> 4;
  float a00 = 0.f, a01 = 0.f, a10 = 0.f, a11 = 0.f;

  for (int d0 = 0; d0 < ND; d0 += 16) {
    // load 32x16 tiles (2 rows per thread)
    #pragma unroll
    for (int rr = 0; rr < 2; ++rr) {
      int r = ty + rr * 16;
      int d = d0 + tx;
      Xs[r][tx] = (i0 + r < n && d < ND) ? X[(size_t)(xr0 + i0 + r) * ND + d] : 0.f;
      Ys[r][tx] = (j0 + r < m && d < ND) ? Y[(size_t)(yr0 + j0 + r) * ND + d] : 0.f;
    }
    __syncthreads();
    #pragma unroll
    for (int dd = 0; dd < 16; ++dd) {
      float x0 = Xs[ty][dd], x1 = Xs[ty + 16][dd];
      float y0 = Ys[tx][dd], y1 = Ys[tx + 16][dd];
      a00 += x0 * y0; a01 += x0 * y1;
      a10 += x1 * y0; a11 += x1 * y1;
    }
    __syncthreads();
  }
  int i = i0 + ty, j = j0 + tx;
  if (i < n) {
    float nx = NX[xr0 + i];
    if (j < m)      C[cbase + (size_t)i * m + j]      = fmaxf(nx + NY[yr0 + j]      - 2.f * a00, 0.f) * CSCALE;
    if (j + 16 < m) C[cbase + (size_t)i * m + j + 16] = fmaxf(nx + NY[yr0 + j + 16] - 2.f * a01, 0.f) * CSCALE;
  }
  if (i + 16 < n) {
    float nx = NX[xr0 + i + 16];
    if (j < m)      C[cbase + (size_t)(i + 16) * m + j]      = fmaxf(nx + NY[yr0 + j]      - 2.f * a10, 0.f) * CSCALE;
    if (j + 16 < m) C[cbase + (size_t)(i + 16) * m + j + 16] = fmaxf(nx + NY[yr0 + j + 16] - 2.f * a11, 0.f) * CSCALE;
  }
}

// ---------------------------------------------------------------- sinkhorn ab  (n=128 rows with logw, m=50 cols uniform 1/50)
__global__ __launch_bounds__(256)
void sinkhorn_ab(const float* __restrict__ Cg, const float* __restrict__ lw2,
                 const float* __restrict__ weight, float* __restrict__ ot) {
  __shared__ float Cs[NL * 51];   // pitch 51 (odd) -> conflict-free-ish
  __shared__ float g2[NR];
  __shared__ float f2[NL];
  __shared__ float h2[NL];        // la2 + f2
  __shared__ float la2s[NL];
  __shared__ float red[4];
  int p = blockIdx.x, b = p / NK, t = threadIdx.x;
  const float* Cp = Cg + (size_t)p * (NL * NR);
  for (int i = t; i < NL * NR; i += 256) {
    int r = i / NR, c = i - r * NR;
    Cs[r * 51 + c] = Cp[i];
  }
  if (t < NL) la2s[t] = lw2[b * NL + t];
  if (t < NR) g2[t] = 0.f;
  __syncthreads();

  for (int it = 0; it < NITER; ++it) {
    // f update: 2 threads per row, logb = -log2(50) hoisted
    {
      int r = t >> 1, sub = t & 1;
      const float* row = &Cs[r * 51];
      float mx = -INFINITY;
      for (int mm = sub; mm < NR; mm += 2) mx = fmaxf(mx, g2[mm] - row[mm]);
      mx = fmaxf(mx, __shfl_xor(mx, 1));
      float s = 0.f;
      for (int mm = sub; mm < NR; mm += 2) s += exp2f(g2[mm] - row[mm] - mx);
      s += __shfl_xor(s, 1);
      if (sub == 0) {
        float fv = LOG2_50 - mx - log2f(s);
        f2[r] = fv; h2[r] = la2s[r] + fv;
      }
    }
    __syncthreads();
    // g update: 4 threads per column, loga carried in h2
    {
      int c = t >> 2, sub = t & 3;
      if (c < NR) {
        float mx = -INFINITY;
        for (int nn = sub; nn < NL; nn += 4) mx = fmaxf(mx, h2[nn] - Cs[nn * 51 + c]);
        mx = fmaxf(mx, __shfl_xor(mx, 1));
        mx = fmaxf(mx, __shfl_xor(mx, 2));
        float s = 0.f;
        for (int nn = sub; nn < NL; nn += 4) s += exp2f(h2[nn] - Cs[nn * 51 + c] - mx);
        s += __shfl_xor(s, 1);
        s += __shfl_xor(s, 2);
        if (sub == 0) g2[c] = -(mx + log2f(s));
      }
    }
    __syncthreads();
  }

  float acc = 0.f;
  if (t < NL) acc = weight[b * NL + t] * f2[t];
  else if (t < NL + NR) acc = g2[t - NL] * (1.0f / NR);
  #pragma unroll
  for (int off = 32; off; off >>= 1) acc += __shfl_xor(acc, off);
  if ((t & 63) == 0) red[t >> 6] = acc;
  __syncthreads();
  if (t == 0) ot[p] = VSCALE * (red[0] + red[1] + red[2] + red[3]);
}

// ---------------------------------------------------------------- sinkhorn aa  (n=m=128, both sides logw)
__global__ __launch_bounds__(512)
void sinkhorn_aa(const float* __restrict__ Cg, const float* __restrict__ lw2,
                 const float* __restrict__ weight, float* __restrict__ ot) {
  __shared__ float Cs[NL * 129];  // 66 KB
  __shared__ float f2[NL], g2[NL], h2[NL], k2[NL], la2s[NL];
  __shared__ float red[8];
  int b = blockIdx.x, t = threadIdx.x;
  const float* Cp = Cg + (size_t)b * (NL * NL);
  for (int i = t; i < NL * NL; i += 512) {
    int r = i >> 7, c = i & 127;
    Cs[r * 129 + c] = Cp[i];
  }
  if (t < NL) { float la = lw2[b * NL + t]; la2s[t] = la; k2[t] = la; } // g2=0 folded
  __syncthreads();

  int r = t >> 2, sub = t & 3;  // r in [0,128)
  for (int it = 0; it < NITER; ++it) {
    // f update: row r, reduce over m; logb in k2 = la2 + g2
    {
      const float* row = &Cs[r * 129];
      float mx = -INFINITY;
      for (int mm = sub; mm < NL; mm += 4) mx = fmaxf(mx, k2[mm] - row[mm]);
      mx = fmaxf(mx, __shfl_xor(mx, 1));
      mx = fmaxf(mx, __shfl_xor(mx, 2));
      float s = 0.f;
      for (int mm = sub; mm < NL; mm += 4) s += exp2f(k2[mm] - row[mm] - mx);
      s += __shfl_xor(s, 1);
      s += __shfl_xor(s, 2);
      if (sub == 0) { float fv = -(mx + log2f(s)); f2[r] = fv; h2[r] = la2s[r] + fv; }
    }
    __syncthreads();
    // g update: column r
    {
      float mx = -INFINITY;
      for (int nn = sub; nn < NL; nn += 4) mx = fmaxf(mx, h2[nn] - Cs[nn * 129 + r]);
      mx = fmaxf(mx, __shfl_xor(mx, 1));
      mx = fmaxf(mx, __shfl_xor(mx, 2));
      float s = 0.f;
      for (int nn = sub; nn < NL; nn += 4) s += exp2f(h2[nn] - Cs[nn * 129 + r] - mx);
      s += __shfl_xor(s, 1);
      s += __shfl_xor(s, 2);
      if (sub == 0) { float gv = -(mx + log2f(s)); g2[r] = gv; k2[r] = la2s[r] + gv; }
    }
    __syncthreads();
  }

  float acc = 0.f;
  if (t < NL) acc = weight[b * NL + t] * (f2[t] + g2[t]);
  #pragma unroll
  for (int off = 32; off; off >>= 1) acc += __shfl_xor(acc, off);
  if ((t & 63) == 0) red[t >> 6] = acc;
  __syncthreads();
  if (t == 0) {
    float v = 0.f;
    #pragma unroll
    for (int i = 0; i < 8; ++i) v += red[i];
    ot[b] = VSCALE * v;
  }
}

// ---------------------------------------------------------------- sinkhorn tt  (n=m=50, both uniform 1/50)
__global__ __launch_bounds__(256)
void sinkhorn_tt(const float* __restrict__ Cg, float* __restrict__ ot) {
  __shared__ float Cs[NR * 51];
  __shared__ float f2[NR], g2[NR];
  __shared__ float red[4];
  int p = blockIdx.x, t = threadIdx.x;
  const float* Cp = Cg + (size_t)p * (NR * NR);
  for (int i = t; i < NR * NR; i += 256) {
    int r = i / NR, c = i - r * NR;
    Cs[r * 51 + c] = Cp[i];
  }
  if (t < NR) g2[t] = 0.f;
  __syncthreads();

  int r = t >> 2, sub = t & 3;
  for (int it = 0; it < NITER; ++it) {
    if (r < NR) {
      const float* row = &Cs[r * 51];
      float mx = -INFINITY;
      for (int mm = sub; mm < NR; mm += 4) mx = fmaxf(mx, g2[mm] - row[mm]);
      mx = fmaxf(mx, __shfl_xor(mx, 1));
      mx = fmaxf(mx, __shfl_xor(mx, 2));
      float s = 0.f;
      for (int mm = sub; mm < NR; mm += 4) s += exp2f(g2[mm] - row[mm] - mx);
      s += __shfl_xor(s, 1);
      s += __shfl_xor(s, 2);
      if (sub == 0) f2[r] = LOG2_50 - mx - log2f(s);
    }
    __syncthreads();
    if (r < NR) {
      float mx = -INFINITY;
      for (int nn = sub; nn < NR; nn += 4) mx = fmaxf(mx, f2[nn] - Cs[nn * 51 + r]);
      mx = fmaxf(mx, __shfl_xor(mx, 1));
      mx = fmaxf(mx, __shfl_xor(mx, 2));
      float s = 0.f;
      for (int nn = sub; nn < NR; nn += 4) s += exp2f(f2[nn] - Cs[nn * 51 + r] - mx);
      s += __shfl_xor(s, 1);
      s += __shfl_xor(s, 2);
      if (sub == 0) g2[r] = LOG2_50 - mx - log2f(s);
    }
    __syncthreads();
  }

  float acc = 0.f;
  if (t < NR) acc = f2[t] + g2[t];
  #pragma unroll
  for (int off = 32; off; off >>= 1) acc += __shfl_xor(acc, off);
  if ((t & 63) == 0) red[t >> 6] = acc;
  __syncthreads();
  if (t == 0) ot[p] = VSCALE * (1.0f / NR) * (red[0] + red[1] + red[2] + red[3]);
}

// ---------------------------------------------------------------- finalize
__global__ void finalize_kernel(const float* __restrict__ oab, const float* __restrict__ oaa,
                                const float* __restrict__ ott, const int* __restrict__ grade,
                                float* __restrict__ out) {
  __shared__ float selft[NK];
  __shared__ float redL[4], redD[4];
  int t = threadIdx.x;
  if (t < NK) selft[t] = ott[t * NK + t];
  __syncthreads();
  float dpart = (t < NK * NK) ? ott[t] : 0.f;
  float lpart = 0.f;
  if (t < NB) {
    int g = grade[t];
    float oa = oaa[t];
    float dpos = oab[t * NK + g] - 0.5f * (oa + selft[g]);
    float s = 0.f;
    #pragma unroll
    for (int k = 0; k < NK; ++k) {
      float dk = oab[t * NK + k] - 0.5f * (oa + selft[k]);
      s += fmaxf(dpos - dk + 10.0f, 0.0f);
    }
    lpart = s - 10.0f;
  }
  #pragma unroll
  for (int off = 32; off; off >>= 1) {
    dpart += __shfl_xor(dpart, off);
    lpart += __shfl_xor(lpart, off);
  }
  if ((t & 63) == 0) { redD[t >> 6] = dpart; redL[t >> 6] = lpart; }
  __syncthreads();
  if (t == 0) {
    float ds = 0.f, ls = 0.f;
    #pragma unroll
    for (int i = 0; i < 4; ++i) { ds += redD[i]; ls += redL[i]; }
    float ss = 0.f;
    #pragma unroll
    for (int k = 0; k < NK; ++k) ss += selft[k];
    float dis = ds - (float)NK * ss;
    out[0] = ls / (float)NB - dis * 0.01f;
  }
}

// ---------------------------------------------------------------- launch
extern "C" void kernel_launch(void* const* d_in, const int* in_sizes, int n_in,
                              void* d_out, int out_size, void* d_ws, size_t ws_size,
                              hipStream_t stream) {
  (void)in_sizes; (void)n_in; (void)out_size; (void)ws_size;
  const float* anchor = (const float*)d_in[0];
  const float* weight = (const float*)d_in[1];
  const float* t0     = (const float*)d_in[2];
  const int*   len    = (const int*)d_in[3];
  const int*   grade  = (const int*)d_in[4];
  float* out = (float*)d_out;

  float* ws  = (float*)d_ws;
  float* Cab = ws;                                    // 128*10*128*50 = 819200
  float* Caa = Cab + (size_t)NB * NK * NL * NR;       // 128*128*128  = 2097152
  float* Ctt = Caa + (size_t)NB * NL * NL;            // 100*50*50    = 250000
  float* na  = Ctt + (size_t)NK * NK * NR * NR;       // 16384
  float* nt  = na + NB * NL;                          // 500
  float* lw2 = nt + NK * NR;                          // 16384
  float* oab = lw2 + NB * NL;                         // 1280
  float* oaa = oab + NB * NK;                         // 128
  float* ott = oaa + NB;                              // 100
  // total ~3.2M floats (~12.8 MB) of workspace

  prep_kernel<<<(NB * NL + NK * NR) / 4, 256, 0, stream>>>(anchor, weight, t0, len, na, nt, lw2);
  cost_kernel<<<dim3(NB * NK, 4, 2), 256, 0, stream>>>(anchor, t0, na, nt, Cab, NL, NR, 0);
  cost_kernel<<<dim3(NB, 4, 4),      256, 0, stream>>>(anchor, anchor, na, na, Caa, NL, NL, 1);
  cost_kernel<<<dim3(NK * NK, 2, 2), 256, 0, stream>>>(t0, t0, nt, nt, Ctt, NR, NR, 2);
  sinkhorn_ab<<<NB * NK, 256, 0, stream>>>(Cab, lw2, weight, oab);
  sinkhorn_aa<<<NB, 512, 0, stream>>>(Caa, lw2, weight, oaa);
  sinkhorn_tt<<<NK * NK, 256, 0, stream>>>(Ctt, ott);
  finalize_kernel<<<1, 256, 0, stream>>>(oab, oaa, ott, grade, out);
}

// Round 2
// 544.949 us; speedup vs baseline: 1.4582x; 1.4582x over previous
//
#include <hip/hip_runtime.h>
#include <math.h>

// Sinkhorn-divergence triplet loss (geomloss-style), MI355X.
// R1: register-resident C + single-pass defer-max LSE in the Sinkhorn kernels.

namespace {
constexpr int NB = 128, NL = 128, ND = 300, NK = 10, NR = 50, NITER = 20;
constexpr float LOG2E   = 1.4426950408889634f;
constexpr float EPS     = 0.0025f;                  // blur^p = 0.05^2
constexpr float CSCALE  = 0.5f * LOG2E / EPS;       // squared-dist -> log2-domain cost
constexpr float VSCALE  = EPS * 0.6931471805599453f; // log2-potential -> nat potential (eps*ln2)
constexpr float LOG2_50 = 5.6438561897747395f;      // log2(50)
constexpr float NEGL2   = -1.442695e9f;             // -1e9 * log2e
constexpr float D_HI    = 30.f, D_LO = -80.f;       // defer-max redo window
}

// ---------------------------------------------------------------- prep
__global__ void prep_kernel(const float* __restrict__ anchor,
                            const float* __restrict__ weight,
                            const float* __restrict__ t0,
                            const int* __restrict__ len,
                            float* __restrict__ na, float* __restrict__ nt,
                            float* __restrict__ lw2) {
  int wid  = (blockIdx.x * blockDim.x + threadIdx.x) >> 6;
  int lane = threadIdx.x & 63;
  const int nA = NB * NL;
  const int total = nA + NK * NR;
  if (wid >= total) return;
  const float* src = (wid < nA) ? (anchor + (size_t)wid * ND)
                                : (t0 + (size_t)(wid - nA) * ND);
  float s = 0.f;
  for (int d = lane; d < ND; d += 64) { float v = src[d]; s += v * v; }
  #pragma unroll
  for (int off = 32; off; off >>= 1) s += __shfl_xor(s, off);
  if (lane == 0) { if (wid < nA) na[wid] = s; else nt[wid - nA] = s; }
  if (wid < nA && lane == 1) {
    int b = wid >> 7, l = wid & 127;
    float w = weight[wid];
    lw2[wid] = (l < len[b]) ? log2f(fmaxf(w, 1e-12f)) : NEGL2;
  }
}

// ---------------------------------------------------------------- cost
__global__ __launch_bounds__(256)
void cost_kernel(const float* __restrict__ X, const float* __restrict__ Y,
                 const float* __restrict__ NX, const float* __restrict__ NY,
                 float* __restrict__ C, int n, int m, int mode) {
  __shared__ float Xs[32][17];
  __shared__ float Ys[32][17];
  int p = blockIdx.x;
  int i0 = blockIdx.y * 32, j0 = blockIdx.z * 32;
  int xr0, yr0;
  if (mode == 0)      { xr0 = (p / NK) * NL; yr0 = (p % NK) * NR; }
  else if (mode == 1) { xr0 = p * NL;        yr0 = xr0;           }
  else                { xr0 = (p / NK) * NR; yr0 = (p % NK) * NR; }
  size_t cbase = (size_t)p * n * m;

  int t  = threadIdx.x;
  int tx = t & 15, ty = t >> 4;
  float a00 = 0.f, a01 = 0.f, a10 = 0.f, a11 = 0.f;

  for (int d0 = 0; d0 < ND; d0 += 16) {
    #pragma unroll
    for (int rr = 0; rr < 2; ++rr) {
      int r = ty + rr * 16;
      int d = d0 + tx;
      Xs[r][tx] = (i0 + r < n && d < ND) ? X[(size_t)(xr0 + i0 + r) * ND + d] : 0.f;
      Ys[r][tx] = (j0 + r < m && d < ND) ? Y[(size_t)(yr0 + j0 + r) * ND + d] : 0.f;
    }
    __syncthreads();
    #pragma unroll
    for (int dd = 0; dd < 16; ++dd) {
      float x0 = Xs[ty][dd], x1 = Xs[ty + 16][dd];
      float y0 = Ys[tx][dd], y1 = Ys[tx + 16][dd];
      a00 += x0 * y0; a01 += x0 * y1;
      a10 += x1 * y0; a11 += x1 * y1;
    }
    __syncthreads();
  }
  int i = i0 + ty, j = j0 + tx;
  if (i < n) {
    float nx = NX[xr0 + i];
    if (j < m)      C[cbase + (size_t)i * m + j]      = fmaxf(nx + NY[yr0 + j]      - 2.f * a00, 0.f) * CSCALE;
    if (j + 16 < m) C[cbase + (size_t)i * m + j + 16] = fmaxf(nx + NY[yr0 + j + 16] - 2.f * a01, 0.f) * CSCALE;
  }
  if (i + 16 < n) {
    float nx = NX[xr0 + i + 16];
    if (j < m)      C[cbase + (size_t)(i + 16) * m + j]      = fmaxf(nx + NY[yr0 + j]      - 2.f * a10, 0.f) * CSCALE;
    if (j + 16 < m) C[cbase + (size_t)(i + 16) * m + j + 16] = fmaxf(nx + NY[yr0 + j + 16] - 2.f * a11, 0.f) * CSCALE;
  }
}

// ---------------------------------------------------------------- sinkhorn ab
// 128x50 per (b,k). Row set: thread t -> row t>>1, 25 cols in regs.
// Col set: thread t<200 -> col t>>2, 32 rows in regs. Single-pass defer-max LSE.
__global__ __launch_bounds__(256)
void sinkhorn_ab(const float* __restrict__ Cg, const float* __restrict__ lw2,
                 const float* __restrict__ weight, float* __restrict__ ot) {
  __shared__ float Cs[NL * 51];   // one-time staging (26 KB)
  __shared__ float g2[NR];
  __shared__ float f2[NL];
  __shared__ float potf2[NL];     // la2 + f2
  __shared__ float la2s[NL];
  __shared__ float red[4];
  int p = blockIdx.x, b = p / NK, t = threadIdx.x;
  const float* Cp = Cg + (size_t)p * (NL * NR);
  for (int i = t; i < NL * NR; i += 256) {
    int r = i / NR, c = i - r * NR;
    Cs[r * 51 + c] = Cp[i];
  }
  if (t < NL) la2s[t] = lw2[b * NL + t];
  if (t < NR) g2[t] = 0.f;
  __syncthreads();

  const int rf = t >> 1, sf = t & 1;     // row set
  float Crow[25];
  {
    const float* rp = &Cs[rf * 51 + sf * 25];
    #pragma unroll
    for (int j = 0; j < 25; ++j) Crow[j] = rp[j];
  }
  const int cc = t >> 2, sc = t & 3;     // col set (t < 200)
  float Ccol[32];
  if (t < 200) {
    #pragma unroll
    for (int i = 0; i < 32; ++i) Ccol[i] = Cs[(sc * 32 + i) * 51 + cc];
  }
  // Cs is never written again -> no barrier needed here.

  float mEf = 0.f, mEg = 0.f;
  const float* gbase = g2 + sf * 25;
  const float* fbase = potf2 + sc * 32;

  for (int it = 0; it < NITER; ++it) {
    // ---- f update: f_r = LOG2_50 - LSE2_m(g2[m] - C[r][m])
    {
      float mx = -3.0e38f, s = 0.f;
      #pragma unroll
      for (int j = 0; j < 25; ++j) {
        float x = gbase[j] - Crow[j];
        mx = fmaxf(mx, x);
        s += exp2f(x - mEf);
      }
      mx = fmaxf(mx, __shfl_xor(mx, 1));
      s += __shfl_xor(s, 1);
      float mU = mEf, d = mx - mEf;
      if (d > D_HI || d < D_LO) {
        mU = mx; s = 0.f;
        #pragma unroll
        for (int j = 0; j < 25; ++j) s += exp2f(gbase[j] - Crow[j] - mx);
        s += __shfl_xor(s, 1);
      }
      mEf = mx;
      if (sf == 0) {
        float fv = LOG2_50 - (mU + log2f(s));
        f2[rf] = fv; potf2[rf] = la2s[rf] + fv;
      }
    }
    __syncthreads();
    // ---- g update: g_c = -LSE2_n(la2[n] + f2[n] - C[n][c])
    if (t < 200) {
      float mx = -3.0e38f, s = 0.f;
      #pragma unroll
      for (int i = 0; i < 32; ++i) {
        float x = fbase[i] - Ccol[i];
        mx = fmaxf(mx, x);
        s += exp2f(x - mEg);
      }
      mx = fmaxf(mx, __shfl_xor(mx, 1));
      mx = fmaxf(mx, __shfl_xor(mx, 2));
      s += __shfl_xor(s, 1);
      s += __shfl_xor(s, 2);
      float mU = mEg, d = mx - mEg;
      if (d > D_HI || d < D_LO) {
        mU = mx; s = 0.f;
        #pragma unroll
        for (int i = 0; i < 32; ++i) s += exp2f(fbase[i] - Ccol[i] - mx);
        s += __shfl_xor(s, 1);
        s += __shfl_xor(s, 2);
      }
      mEg = mx;
      if (sc == 0) g2[cc] = -(mU + log2f(s));
    }
    __syncthreads();
  }

  float acc = 0.f;
  if (t < NL) acc = weight[b * NL + t] * f2[t];
  else if (t < NL + NR) acc = g2[t - NL] * (1.0f / NR);
  #pragma unroll
  for (int off = 32; off; off >>= 1) acc += __shfl_xor(acc, off);
  if ((t & 63) == 0) red[t >> 6] = acc;
  __syncthreads();
  if (t == 0) ot[p] = VSCALE * (red[0] + red[1] + red[2] + red[3]);
}

// ---------------------------------------------------------------- sinkhorn aa
// C symmetric, equal marginals -> one register set serves both orientations.
// 512 threads: thread = (row r = t>>2, sub = t&3 owning cols sub*32..+32).
__global__ __launch_bounds__(512)
void sinkhorn_aa(const float* __restrict__ Cg, const float* __restrict__ lw2,
                 const float* __restrict__ weight, float* __restrict__ ot) {
  __shared__ float pF[NL];
  __shared__ float pG[NL];
  __shared__ float red[8];
  int b = blockIdx.x, t = threadIdx.x;
  int r = t >> 2, sub = t & 3;
  const float* Cp = Cg + (size_t)b * (NL * NL) + (size_t)r * NL + sub * 32;
  const float* lp = lw2 + b * NL + sub * 32;
  float Cr[32];   // la2[col] - C[r][col]
  #pragma unroll
  for (int i = 0; i < 32; i += 4) {
    float4 cv = *(const float4*)(Cp + i);
    float4 lv = *(const float4*)(lp + i);
    Cr[i]     = lv.x - cv.x; Cr[i + 1] = lv.y - cv.y;
    Cr[i + 2] = lv.z - cv.z; Cr[i + 3] = lv.w - cv.w;
  }
  if (t < NL) pG[t] = 0.f;
  __syncthreads();

  float mE = 0.f;
  for (int app = 0; app < 2 * NITER; ++app) {
    const float* src = (app & 1) ? pF : pG;   // even: f = T(g), odd: g = T(f)
    float* dst       = (app & 1) ? pG : pF;
    const float* sp = src + sub * 32;
    float mx = -3.0e38f, s = 0.f;
    #pragma unroll
    for (int i = 0; i < 32; ++i) {
      float x = sp[i] + Cr[i];
      mx = fmaxf(mx, x);
      s += exp2f(x - mE);
    }
    mx = fmaxf(mx, __shfl_xor(mx, 1));
    mx = fmaxf(mx, __shfl_xor(mx, 2));
    s += __shfl_xor(s, 1);
    s += __shfl_xor(s, 2);
    float mU = mE, d = mx - mE;
    if (d > D_HI || d < D_LO) {
      mU = mx; s = 0.f;
      #pragma unroll
      for (int i = 0; i < 32; ++i) s += exp2f(sp[i] + Cr[i] - mx);
      s += __shfl_xor(s, 1);
      s += __shfl_xor(s, 2);
    }
    mE = mx;
    if (sub == 0) dst[r] = -(mU + log2f(s));
    __syncthreads();
  }

  float acc = 0.f;
  if (t < NL) acc = weight[b * NL + t] * (pF[t] + pG[t]);
  #pragma unroll
  for (int off = 32; off; off >>= 1) acc += __shfl_xor(acc, off);
  if ((t & 63) == 0) red[t >> 6] = acc;
  __syncthreads();
  if (t == 0) {
    float v = 0.f;
    #pragma unroll
    for (int i = 0; i < 8; ++i) v += red[i];
    ot[b] = VSCALE * v;
  }
}

// ---------------------------------------------------------------- sinkhorn tt  (n=m=50, both uniform 1/50)
__global__ __launch_bounds__(256)
void sinkhorn_tt(const float* __restrict__ Cg, float* __restrict__ ot) {
  __shared__ float Cs[NR * 51];
  __shared__ float f2[NR], g2[NR];
  __shared__ float red[4];
  int p = blockIdx.x, t = threadIdx.x;
  const float* Cp = Cg + (size_t)p * (NR * NR);
  for (int i = t; i < NR * NR; i += 256) {
    int r = i / NR, c = i - r * NR;
    Cs[r * 51 + c] = Cp[i];
  }
  if (t < NR) g2[t] = 0.f;
  __syncthreads();

  int r = t >> 2, sub = t & 3;
  for (int it = 0; it < NITER; ++it) {
    if (r < NR) {
      const float* row = &Cs[r * 51];
      float mx = -INFINITY;
      for (int mm = sub; mm < NR; mm += 4) mx = fmaxf(mx, g2[mm] - row[mm]);
      mx = fmaxf(mx, __shfl_xor(mx, 1));
      mx = fmaxf(mx, __shfl_xor(mx, 2));
      float s = 0.f;
      for (int mm = sub; mm < NR; mm += 4) s += exp2f(g2[mm] - row[mm] - mx);
      s += __shfl_xor(s, 1);
      s += __shfl_xor(s, 2);
      if (sub == 0) f2[r] = LOG2_50 - mx - log2f(s);
    }
    __syncthreads();
    if (r < NR) {
      float mx = -INFINITY;
      for (int nn = sub; nn < NR; nn += 4) mx = fmaxf(mx, f2[nn] - Cs[nn * 51 + r]);
      mx = fmaxf(mx, __shfl_xor(mx, 1));
      mx = fmaxf(mx, __shfl_xor(mx, 2));
      float s = 0.f;
      for (int nn = sub; nn < NR; nn += 4) s += exp2f(f2[nn] - Cs[nn * 51 + r] - mx);
      s += __shfl_xor(s, 1);
      s += __shfl_xor(s, 2);
      if (sub == 0) g2[r] = LOG2_50 - mx - log2f(s);
    }
    __syncthreads();
  }

  float acc = 0.f;
  if (t < NR) acc = f2[t] + g2[t];
  #pragma unroll
  for (int off = 32; off; off >>= 1) acc += __shfl_xor(acc, off);
  if ((t & 63) == 0) red[t >> 6] = acc;
  __syncthreads();
  if (t == 0) ot[p] = VSCALE * (1.0f / NR) * (red[0] + red[1] + red[2] + red[3]);
}

// ---------------------------------------------------------------- finalize
__global__ void finalize_kernel(const float* __restrict__ oab, const float* __restrict__ oaa,
                                const float* __restrict__ ott, const int* __restrict__ grade,
                                float* __restrict__ out) {
  __shared__ float selft[NK];
  __shared__ float redL[4], redD[4];
  int t = threadIdx.x;
  if (t < NK) selft[t] = ott[t * NK + t];
  __syncthreads();
  float dpart = (t < NK * NK) ? ott[t] : 0.f;
  float lpart = 0.f;
  if (t < NB) {
    int g = grade[t];
    float oa = oaa[t];
    float dpos = oab[t * NK + g] - 0.5f * (oa + selft[g]);
    float s = 0.f;
    #pragma unroll
    for (int k = 0; k < NK; ++k) {
      float dk = oab[t * NK + k] - 0.5f * (oa + selft[k]);
      s += fmaxf(dpos - dk + 10.0f, 0.0f);
    }
    lpart = s - 10.0f;
  }
  #pragma unroll
  for (int off = 32; off; off >>= 1) {
    dpart += __shfl_xor(dpart, off);
    lpart += __shfl_xor(lpart, off);
  }
  if ((t & 63) == 0) { redD[t >> 6] = dpart; redL[t >> 6] = lpart; }
  __syncthreads();
  if (t == 0) {
    float ds = 0.f, ls = 0.f;
    #pragma unroll
    for (int i = 0; i < 4; ++i) { ds += redD[i]; ls += redL[i]; }
    float ss = 0.f;
    #pragma unroll
    for (int k = 0; k < NK; ++k) ss += selft[k];
    float dis = ds - (float)NK * ss;
    out[0] = ls / (float)NB - dis * 0.01f;
  }
}

// ---------------------------------------------------------------- launch
extern "C" void kernel_launch(void* const* d_in, const int* in_sizes, int n_in,
                              void* d_out, int out_size, void* d_ws, size_t ws_size,
                              hipStream_t stream) {
  (void)in_sizes; (void)n_in; (void)out_size; (void)ws_size;
  const float* anchor = (const float*)d_in[0];
  const float* weight = (const float*)d_in[1];
  const float* t0     = (const float*)d_in[2];
  const int*   len    = (const int*)d_in[3];
  const int*   grade  = (const int*)d_in[4];
  float* out = (float*)d_out;

  float* ws  = (float*)d_ws;
  float* Cab = ws;                                    // 819200
  float* Caa = Cab + (size_t)NB * NK * NL * NR;       // 2097152
  float* Ctt = Caa + (size_t)NB * NL * NL;            // 250000
  float* na  = Ctt + (size_t)NK * NK * NR * NR;       // 16384
  float* nt  = na + NB * NL;                          // 500
  float* lw2 = nt + NK * NR;                          // 16384
  float* oab = lw2 + NB * NL;                         // 1280
  float* oaa = oab + NB * NK;                         // 128
  float* ott = oaa + NB;                              // 100

  prep_kernel<<<(NB * NL + NK * NR) / 4, 256, 0, stream>>>(anchor, weight, t0, len, na, nt, lw2);
  cost_kernel<<<dim3(NB * NK, 4, 2), 256, 0, stream>>>(anchor, t0, na, nt, Cab, NL, NR, 0);
  cost_kernel<<<dim3(NB, 4, 4),      256, 0, stream>>>(anchor, anchor, na, na, Caa, NL, NL, 1);
  cost_kernel<<<dim3(NK * NK, 2, 2), 256, 0, stream>>>(t0, t0, nt, nt, Ctt, NR, NR, 2);
  sinkhorn_ab<<<NB * NK, 256, 0, stream>>>(Cab, lw2, weight, oab);
  sinkhorn_aa<<<NB, 512, 0, stream>>>(Caa, lw2, weight, oaa);
  sinkhorn_tt<<<NK * NK, 256, 0, stream>>>(Ctt, ott);
  finalize_kernel<<<1, 256, 0, stream>>>(oab, oaa, ott, grade, out);
}